// Round 1
// baseline (774.952 us; speedup 1.0000x reference)
//
#include <hip/hip_runtime.h>
#include <math.h>

#define Bn 16
#define Sn 512
#define Hn 768
#define NHn 12
#define DHn 64
#define In 3072
#define TOK (Bn*Sn)

typedef unsigned short u16;
typedef short bf16x8 __attribute__((ext_vector_type(8)));
typedef float f32x4 __attribute__((ext_vector_type(4)));

__device__ __forceinline__ u16 f2bf(float x) {
    union { float f; unsigned u; } v; v.f = x;
    unsigned r = v.u + 0x7FFF + ((v.u >> 16) & 1);
    return (u16)(r >> 16);
}
__device__ __forceinline__ float bf2f(u16 u) {
    union { unsigned u; float f; } v; v.u = ((unsigned)u) << 16; return v.f;
}

// ---------------- elementwise f32 -> bf16 ----------------
__global__ __launch_bounds__(256) void k_cvt(const float* __restrict__ in, u16* __restrict__ out, int n) {
    int i = (blockIdx.x * 256 + threadIdx.x) * 8;
    if (i + 8 > n) return;
    float4 a = *(const float4*)(in + i);
    float4 b = *(const float4*)(in + i + 4);
    bf16x8 o;
    o[0] = (short)f2bf(a.x); o[1] = (short)f2bf(a.y); o[2] = (short)f2bf(a.z); o[3] = (short)f2bf(a.w);
    o[4] = (short)f2bf(b.x); o[5] = (short)f2bf(b.y); o[6] = (short)f2bf(b.z); o[7] = (short)f2bf(b.w);
    *(bf16x8*)(out + i) = o;
}

// ---------------- weight transpose f32[K,N] -> bf16[N,K] ----------------
__global__ __launch_bounds__(256) void k_transpose(const float* __restrict__ W, u16* __restrict__ Wt, int K, int N) {
    __shared__ float tile[32][33];
    int n0 = blockIdx.x * 32, k0 = blockIdx.y * 32;
    int tx = threadIdx.x, ty = threadIdx.y;  // (32,8)
    #pragma unroll
    for (int i = 0; i < 32; i += 8)
        tile[ty + i][tx] = W[(size_t)(k0 + ty + i) * N + n0 + tx];
    __syncthreads();
    #pragma unroll
    for (int i = 0; i < 32; i += 8)
        Wt[(size_t)(n0 + ty + i) * K + k0 + tx] = f2bf(tile[tx][ty + i]);
}

__global__ __launch_bounds__(256) void k_pack_bias(const float* __restrict__ bq, const float* __restrict__ bk,
                                                   const float* __restrict__ bv, float* __restrict__ bqkv) {
    int i = blockIdx.x * 256 + threadIdx.x;
    if (i < 2304) bqkv[i] = (i < 768) ? bq[i] : (i < 1536 ? bk[i - 768] : bv[i - 1536]);
}

// ---------------- generic bf16 MFMA GEMM: C[M,N] = A[M,K] @ Bt[N,K]^T + bias ----------------
#define GM_BF16 0
#define GM_F32 1
#define GM_GELU_BF16 2

__global__ __launch_bounds__(256) void k_gemm(const u16* __restrict__ A, const u16* __restrict__ Bt,
                                              const float* __restrict__ bias, void* __restrict__ Cout,
                                              int M, int N, int K, int mode) {
    __shared__ __align__(16) u16 sA[128 * 40];
    __shared__ __align__(16) u16 sB[128 * 40];
    int tid = threadIdx.x;
    int wave = tid >> 6, lane = tid & 63;
    int lane16 = lane & 15, quad = lane >> 4;
    int m0 = blockIdx.y * 128, n0 = blockIdx.x * 128;
    int wm = (wave >> 1) * 64, wn = (wave & 1) * 64;
    f32x4 acc[4][4] = {};

    for (int k0 = 0; k0 < K; k0 += 32) {
        __syncthreads();
        #pragma unroll
        for (int rep = 0; rep < 2; rep++) {
            int cc = tid + rep * 256;
            int row = cc >> 2, off = (cc & 3) * 8;
            *(bf16x8*)&sA[row * 40 + off] = *(const bf16x8*)&A[(size_t)(m0 + row) * K + k0 + off];
            *(bf16x8*)&sB[row * 40 + off] = *(const bf16x8*)&Bt[(size_t)(n0 + row) * K + k0 + off];
        }
        __syncthreads();
        bf16x8 af[4], bfr[4];
        #pragma unroll
        for (int t = 0; t < 4; t++) af[t]  = *(const bf16x8*)&sA[(wm + t * 16 + lane16) * 40 + quad * 8];
        #pragma unroll
        for (int t = 0; t < 4; t++) bfr[t] = *(const bf16x8*)&sB[(wn + t * 16 + lane16) * 40 + quad * 8];
        #pragma unroll
        for (int tm = 0; tm < 4; tm++)
            #pragma unroll
            for (int tn = 0; tn < 4; tn++)
                acc[tm][tn] = __builtin_amdgcn_mfma_f32_16x16x32_bf16(af[tm], bfr[tn], acc[tm][tn], 0, 0, 0);
    }

    float* Cf = (float*)Cout;
    u16* Ch = (u16*)Cout;
    #pragma unroll
    for (int tm = 0; tm < 4; tm++) {
        #pragma unroll
        for (int tn = 0; tn < 4; tn++) {
            int col = n0 + wn + tn * 16 + lane16;
            float bv_ = bias ? bias[col] : 0.f;
            #pragma unroll
            for (int r = 0; r < 4; r++) {
                int row = m0 + wm + tm * 16 + quad * 4 + r;
                float v = acc[tm][tn][r] + bv_;
                if (mode == GM_GELU_BF16) {
                    v = 0.5f * v * (1.f + erff(v * 0.70710678118654752f));
                    Ch[(size_t)row * N + col] = f2bf(v);
                } else if (mode == GM_BF16) {
                    Ch[(size_t)row * N + col] = f2bf(v);
                } else {
                    Cf[(size_t)row * N + col] = v;
                }
            }
        }
    }
}

// ---------------- V transpose: qkv[tok, 1536+h*64+d] -> Vt[(b,h), d, j] ----------------
__global__ __launch_bounds__(256) void k_vt(const u16* __restrict__ qkv, u16* __restrict__ Vt) {
    __shared__ u16 s[64][72];
    int z = blockIdx.y;  // b*12+h
    int j0 = blockIdx.x * 64;
    int b = z / NHn, h = z % NHn;
    int t = threadIdx.x;
    for (int e = t; e < 4096; e += 256) {
        int j = e >> 6, d = e & 63;
        s[j][d] = qkv[(size_t)(b * Sn + j0 + j) * 2304 + 1536 + h * 64 + d];
    }
    __syncthreads();
    for (int e = t; e < 4096; e += 256) {
        int d = e >> 6, jj = e & 63;
        Vt[((size_t)z * 64 + d) * Sn + j0 + jj] = s[jj][d];
    }
}

// ---------------- disentangled scores: c2c + windowed c2p + p2c ----------------
__global__ __launch_bounds__(256) void k_scores(const u16* __restrict__ qkv, const u16* __restrict__ posk,
                                                const u16* __restrict__ posq, u16* __restrict__ scores) {
    __shared__ __align__(16) u16 sQ[64 * 72];
    __shared__ __align__(16) u16 sK[64 * 72];
    __shared__ __align__(16) u16 sT1[64 * 136];  // c2p tmp, bf16
    __shared__ __align__(16) u16 sT2[64 * 136];  // p2c tmp, bf16
    int z = blockIdx.z;
    int b = z / NHn, h = z % NHn;
    int i0 = blockIdx.y * 64, j0 = blockIdx.x * 64;
    int t = threadIdx.x, wave = t >> 6, lane = t & 63;
    int lane16 = lane & 15, quad = lane >> 4;

    for (int e = t; e < 512; e += 256) {
        int r = e >> 3, c = (e & 7) * 8;
        *(bf16x8*)&sQ[r * 72 + c] = *(const bf16x8*)&qkv[(size_t)(b * Sn + i0 + r) * 2304 + 0   + h * 64 + c];
        *(bf16x8*)&sK[r * 72 + c] = *(const bf16x8*)&qkv[(size_t)(b * Sn + j0 + r) * 2304 + 768 + h * 64 + c];
    }
    __syncthreads();

    int r0pk = i0 - j0 + 449;  // window base into posk rows
    int r0pq = j0 - i0 + 449;
    const u16* pkh = posk + h * 64;
    const u16* pqh = posq + h * 64;

    // tmp1[i, t] = q_i . posk[r0pk+t];  tmp2[j, t] = k_j . posq[r0pq+t]
    for (int tr = 0; tr < 8; tr++) {
        f32x4 a1 = {}, a2 = {};
        int rPK = min(r0pk + tr * 16 + lane16, 1023);
        int rPQ = min(r0pq + tr * 16 + lane16, 1023);
        #pragma unroll
        for (int kk = 0; kk < 2; kk++) {
            bf16x8 aq  = *(const bf16x8*)&sQ[(wave * 16 + lane16) * 72 + kk * 32 + quad * 8];
            bf16x8 ak  = *(const bf16x8*)&sK[(wave * 16 + lane16) * 72 + kk * 32 + quad * 8];
            bf16x8 bpk = *(const bf16x8*)&pkh[(size_t)rPK * Hn + kk * 32 + quad * 8];
            bf16x8 bpq = *(const bf16x8*)&pqh[(size_t)rPQ * Hn + kk * 32 + quad * 8];
            a1 = __builtin_amdgcn_mfma_f32_16x16x32_bf16(aq, bpk, a1, 0, 0, 0);
            a2 = __builtin_amdgcn_mfma_f32_16x16x32_bf16(ak, bpq, a2, 0, 0, 0);
        }
        #pragma unroll
        for (int r = 0; r < 4; r++) {
            sT1[(wave * 16 + quad * 4 + r) * 136 + tr * 16 + lane16] = f2bf(a1[r]);
            sT2[(wave * 16 + quad * 4 + r) * 136 + tr * 16 + lane16] = f2bf(a2[r]);
        }
    }
    __syncthreads();

    const float scale = 0.07216878364870323f;  // 1/sqrt(3*64)
    #pragma unroll
    for (int tn = 0; tn < 4; tn++) {
        f32x4 acc = {};
        #pragma unroll
        for (int kk = 0; kk < 2; kk++) {
            bf16x8 aq = *(const bf16x8*)&sQ[(wave * 16 + lane16) * 72 + kk * 32 + quad * 8];
            bf16x8 bk = *(const bf16x8*)&sK[(tn * 16 + lane16) * 72 + kk * 32 + quad * 8];
            acc = __builtin_amdgcn_mfma_f32_16x16x32_bf16(aq, bk, acc, 0, 0, 0);
        }
        #pragma unroll
        for (int r = 0; r < 4; r++) {
            int row = wave * 16 + quad * 4 + r;  // local i
            int col = tn * 16 + lane16;          // local j
            float v = acc[r] + bf2f(sT1[row * 136 + (row - col + 63)])
                             + bf2f(sT2[col * 136 + (col - row + 63)]);
            scores[((size_t)z * Sn + i0 + row) * Sn + j0 + col] = f2bf(v * scale);
        }
    }
}

// ---------------- softmax (in-place, row = (b*12+h)*512 + i) ----------------
__global__ __launch_bounds__(256) void k_softmax(u16* __restrict__ scores, const float* __restrict__ mask) {
    int wave = threadIdx.x >> 6, lane = threadIdx.x & 63;
    long row = (long)blockIdx.x * 4 + wave;
    int b = (int)(row / (NHn * Sn));
    u16* p = scores + (size_t)row * Sn + lane * 8;
    const float* mrow = mask + (size_t)b * Sn + lane * 8;
    bf16x8 v = *(const bf16x8*)p;
    float s[8];
    #pragma unroll
    for (int j = 0; j < 8; j++) {
        float x = bf2f((u16)v[j]);
        s[j] = (mrow[j] > 0.f) ? x : -1e9f;
    }
    float mx = s[0];
    #pragma unroll
    for (int j = 1; j < 8; j++) mx = fmaxf(mx, s[j]);
    for (int off = 32; off; off >>= 1) mx = fmaxf(mx, __shfl_xor(mx, off));
    float sum = 0.f;
    #pragma unroll
    for (int j = 0; j < 8; j++) { s[j] = expf(s[j] - mx); sum += s[j]; }
    for (int off = 32; off; off >>= 1) sum += __shfl_xor(sum, off);
    float inv = 1.f / sum;
    bf16x8 o;
    #pragma unroll
    for (int j = 0; j < 8; j++) o[j] = (short)f2bf(s[j] * inv);
    *(bf16x8*)p = o;
}

// ---------------- attn @ V -> ctx bf16 [tok, h*64+d] ----------------
__global__ __launch_bounds__(256) void k_av(const u16* __restrict__ attn, const u16* __restrict__ Vt,
                                            u16* __restrict__ ctx) {
    __shared__ __align__(16) u16 sP[64 * 72];
    __shared__ __align__(16) u16 sV[64 * 72];
    int z = blockIdx.y;
    int b = z / NHn, h = z % NHn;
    int i0 = blockIdx.x * 64;
    int t = threadIdx.x, wave = t >> 6, lane = t & 63;
    int lane16 = lane & 15, quad = lane >> 4;
    f32x4 acc[4] = {};
    for (int j0 = 0; j0 < Sn; j0 += 64) {
        __syncthreads();
        for (int e = t; e < 512; e += 256) {
            int r = e >> 3, c = (e & 7) * 8;
            *(bf16x8*)&sP[r * 72 + c] = *(const bf16x8*)&attn[((size_t)z * Sn + i0 + r) * Sn + j0 + c];
            *(bf16x8*)&sV[r * 72 + c] = *(const bf16x8*)&Vt[((size_t)z * 64 + r) * Sn + j0 + c];
        }
        __syncthreads();
        #pragma unroll
        for (int kk = 0; kk < 2; kk++) {
            bf16x8 a = *(const bf16x8*)&sP[(wave * 16 + lane16) * 72 + kk * 32 + quad * 8];
            #pragma unroll
            for (int tn = 0; tn < 4; tn++) {
                bf16x8 bv = *(const bf16x8*)&sV[(tn * 16 + lane16) * 72 + kk * 32 + quad * 8];
                acc[tn] = __builtin_amdgcn_mfma_f32_16x16x32_bf16(a, bv, acc[tn], 0, 0, 0);
            }
        }
    }
    #pragma unroll
    for (int tn = 0; tn < 4; tn++)
        #pragma unroll
        for (int r = 0; r < 4; r++) {
            int row = i0 + wave * 16 + quad * 4 + r;  // i
            int col = tn * 16 + lane16;               // d
            ctx[(size_t)(b * Sn + row) * Hn + h * 64 + col] = f2bf(acc[tn][r]);
        }
}

// ---------------- residual + layernorm (optionally also bf16 copy) ----------------
__global__ __launch_bounds__(256) void k_ln(const float* __restrict__ x1, const float* __restrict__ x2,
                                            const float* __restrict__ g, const float* __restrict__ bb,
                                            float* __restrict__ outf, u16* __restrict__ outh) {
    int row = blockIdx.x, t = threadIdx.x;
    const float* p1 = x1 + (size_t)row * Hn;
    const float* p2 = x2 + (size_t)row * Hn;
    float x[3], s1 = 0.f, s2 = 0.f;
    #pragma unroll
    for (int i = 0; i < 3; i++) {
        int c = t + i * 256;
        float v = p1[c] + p2[c];
        x[i] = v; s1 += v; s2 += v * v;
    }
    for (int off = 32; off; off >>= 1) { s1 += __shfl_xor(s1, off); s2 += __shfl_xor(s2, off); }
    __shared__ float a1[4], a2[4];
    if ((t & 63) == 0) { a1[t >> 6] = s1; a2[t >> 6] = s2; }
    __syncthreads();
    s1 = a1[0] + a1[1] + a1[2] + a1[3];
    s2 = a2[0] + a2[1] + a2[2] + a2[3];
    float mu = s1 * (1.f / 768.f);
    float var = s2 * (1.f / 768.f) - mu * mu;
    float rs = rsqrtf(var + 1e-7f);
    #pragma unroll
    for (int i = 0; i < 3; i++) {
        int c = t + i * 256;
        float y = (x[i] - mu) * rs * g[c] + bb[c];
        outf[(size_t)row * Hn + c] = y;
        if (outh) outh[(size_t)row * Hn + c] = f2bf(y);
    }
}

extern "C" void kernel_launch(void* const* d_in, const int* in_sizes, int n_in,
                              void* d_out, int out_size, void* d_ws, size_t ws_size,
                              hipStream_t stream) {
    const float* hs   = (const float*)d_in[0];
    const float* mask = (const float*)d_in[1];
    const float* pos  = (const float*)d_in[2];
    const float* Wq = (const float*)d_in[3],  *bq = (const float*)d_in[4];
    const float* Wk = (const float*)d_in[5],  *bk = (const float*)d_in[6];
    const float* Wv = (const float*)d_in[7],  *bv = (const float*)d_in[8];
    const float* Wpk = (const float*)d_in[9], *Wpq = (const float*)d_in[10];
    const float* Wo = (const float*)d_in[11], *bo = (const float*)d_in[12];
    const float* g1 = (const float*)d_in[13], *b1ln = (const float*)d_in[14];
    const float* W1 = (const float*)d_in[15], *b1f = (const float*)d_in[16];
    const float* W2 = (const float*)d_in[17], *b2f = (const float*)d_in[18];
    const float* g2 = (const float*)d_in[19], *b2ln = (const float*)d_in[20];
    float* out = (float*)d_out;

    char* w = (char*)d_ws;
    u16*  X16    = (u16*)w;                 w += 12582912;   // [8192,768] bf16
    u16*  pos16  = (u16*)w;                 w += 1572864;    // [1024,768] bf16
    u16*  WqkvT  = (u16*)w;                 w += 3538944;    // [2304,768] bf16
    float* bqkv  = (float*)w;               w += 9216;       // [2304]
    u16*  WoT    = (u16*)w;                 w += 1179648;    // [768,768]
    u16*  W1T    = (u16*)w;                 w += 4718592;    // [3072,768]
    u16*  W2T    = (u16*)w;                 w += 4718592;    // [768,3072]
    u16*  WpkT   = (u16*)w;                 w += 1179648;
    u16*  WpqT   = (u16*)w;                 w += 1179648;
    u16*  posk   = (u16*)w;                 w += 1572864;    // [1024, h*64+d]
    u16*  posq   = (u16*)w;                 w += 1572864;
    u16*  qkv    = (u16*)w;                 w += 37748736;   // [8192,2304] bf16
    u16*  Vt     = (u16*)w;                 w += 12582912;   // [192,64,512] bf16
    u16*  scores = (u16*)w;                 w += 100663296;  // [192,512,512] bf16
    float* attnout = (float*)w;             w += 25165824;   // [8192,768] f32
    // aliases (lifetime-disjoint)
    u16*  ctx  = qkv;                         // written by AV after q,k,v dead
    float* h1f = (float*)scores;              // after attn consumed
    u16*  ffn1 = (u16*)((char*)scores + 25165824);
    u16*  h1h  = X16;                         // X16 dead after qkv GEMM
    float* ffn2 = attnout;                    // attnout dead after LN1

    // prep: converts + weight transposes
    k_cvt<<<3072, 256, 0, stream>>>(hs, X16, TOK * Hn);
    k_cvt<<<384, 256, 0, stream>>>(pos, pos16, 1024 * Hn);
    dim3 tb(32, 8);
    k_transpose<<<dim3(24, 24), tb, 0, stream>>>(Wq, WqkvT, 768, 768);
    k_transpose<<<dim3(24, 24), tb, 0, stream>>>(Wk, WqkvT + 589824, 768, 768);
    k_transpose<<<dim3(24, 24), tb, 0, stream>>>(Wv, WqkvT + 1179648, 768, 768);
    k_transpose<<<dim3(24, 24), tb, 0, stream>>>(Wo, WoT, 768, 768);
    k_transpose<<<dim3(96, 24), tb, 0, stream>>>(W1, W1T, 768, 3072);
    k_transpose<<<dim3(24, 96), tb, 0, stream>>>(W2, W2T, 3072, 768);
    k_transpose<<<dim3(24, 24), tb, 0, stream>>>(Wpk, WpkT, 768, 768);
    k_transpose<<<dim3(24, 24), tb, 0, stream>>>(Wpq, WpqT, 768, 768);
    k_pack_bias<<<9, 256, 0, stream>>>(bq, bk, bv, bqkv);

    // projections
    k_gemm<<<dim3(18, 64), 256, 0, stream>>>(X16, WqkvT, bqkv, qkv, TOK, 2304, 768, GM_BF16);
    k_gemm<<<dim3(6, 8), 256, 0, stream>>>(pos16, WpkT, nullptr, posk, 1024, 768, 768, GM_BF16);
    k_gemm<<<dim3(6, 8), 256, 0, stream>>>(pos16, WpqT, nullptr, posq, 1024, 768, 768, GM_BF16);

    // attention
    k_vt<<<dim3(8, 192), 256, 0, stream>>>(qkv, Vt);
    k_scores<<<dim3(8, 8, 192), 256, 0, stream>>>(qkv, posk, posq, scores);
    k_softmax<<<24576, 256, 0, stream>>>(scores, mask);
    k_av<<<dim3(8, 192), 256, 0, stream>>>(scores, Vt, ctx);
    k_gemm<<<dim3(6, 64), 256, 0, stream>>>(ctx, WoT, bo, attnout, TOK, 768, 768, GM_F32);
    k_ln<<<TOK, 256, 0, stream>>>(hs, attnout, g1, b1ln, h1f, h1h);

    // FFN
    k_gemm<<<dim3(24, 64), 256, 0, stream>>>(h1h, W1T, b1f, ffn1, TOK, 3072, 768, GM_GELU_BF16);
    k_gemm<<<dim3(6, 64), 256, 0, stream>>>(ffn1, W2T, b2f, ffn2, TOK, 768, 3072, GM_F32);
    k_ln<<<TOK, 256, 0, stream>>>(h1f, ffn2, g2, b2ln, out, nullptr);
}

// Round 2
// 737.598 us; speedup vs baseline: 1.0506x; 1.0506x over previous
//
#include <hip/hip_runtime.h>
#include <math.h>

#define Bn 16
#define Sn 512
#define Hn 768
#define NHn 12
#define DHn 64
#define In 3072
#define TOK (Bn*Sn)

typedef unsigned short u16;
typedef short bf16x8 __attribute__((ext_vector_type(8)));
typedef float f32x4 __attribute__((ext_vector_type(4)));

__device__ __forceinline__ u16 f2bf(float x) {
    union { float f; unsigned u; } v; v.f = x;
    unsigned r = v.u + 0x7FFF + ((v.u >> 16) & 1);
    return (u16)(r >> 16);
}
__device__ __forceinline__ float bf2f(u16 u) {
    union { unsigned u; float f; } v; v.u = ((unsigned)u) << 16; return v.f;
}

// ---------------- elementwise f32 -> bf16 ----------------
__global__ __launch_bounds__(256) void k_cvt(const float* __restrict__ in, u16* __restrict__ out, int n) {
    int i = (blockIdx.x * 256 + threadIdx.x) * 8;
    if (i + 8 > n) return;
    float4 a = *(const float4*)(in + i);
    float4 b = *(const float4*)(in + i + 4);
    bf16x8 o;
    o[0] = (short)f2bf(a.x); o[1] = (short)f2bf(a.y); o[2] = (short)f2bf(a.z); o[3] = (short)f2bf(a.w);
    o[4] = (short)f2bf(b.x); o[5] = (short)f2bf(b.y); o[6] = (short)f2bf(b.z); o[7] = (short)f2bf(b.w);
    *(bf16x8*)(out + i) = o;
}

// ---------------- weight transpose f32[K,N] -> bf16[N,K] ----------------
__global__ __launch_bounds__(256) void k_transpose(const float* __restrict__ W, u16* __restrict__ Wt, int K, int N) {
    __shared__ float tile[32][33];
    int n0 = blockIdx.x * 32, k0 = blockIdx.y * 32;
    int tx = threadIdx.x, ty = threadIdx.y;  // (32,8)
    #pragma unroll
    for (int i = 0; i < 32; i += 8)
        tile[ty + i][tx] = W[(size_t)(k0 + ty + i) * N + n0 + tx];
    __syncthreads();
    #pragma unroll
    for (int i = 0; i < 32; i += 8)
        Wt[(size_t)(n0 + ty + i) * K + k0 + tx] = f2bf(tile[tx][ty + i]);
}

__global__ __launch_bounds__(256) void k_pack_bias(const float* __restrict__ bq, const float* __restrict__ bk,
                                                   const float* __restrict__ bv, float* __restrict__ bqkv) {
    int i = blockIdx.x * 256 + threadIdx.x;
    if (i < 2304) bqkv[i] = (i < 768) ? bq[i] : (i < 1536 ? bk[i - 768] : bv[i - 1536]);
}

// ---------------- generic bf16 MFMA GEMM: C[M,N] = A[M,K] @ Bt[N,K]^T + bias ----------------
#define GM_BF16 0
#define GM_F32 1
#define GM_GELU_BF16 2
#define GM_POSH 3   // write bf16 to [h][r][d] layout: h=col>>6, d=col&63, idx=h*65536+row*64+d

__global__ __launch_bounds__(256) void k_gemm(const u16* __restrict__ A, const u16* __restrict__ Bt,
                                              const float* __restrict__ bias, void* __restrict__ Cout,
                                              int M, int N, int K, int mode) {
    __shared__ __align__(16) u16 sA[128 * 40];
    __shared__ __align__(16) u16 sB[128 * 40];
    int tid = threadIdx.x;
    int wave = tid >> 6, lane = tid & 63;
    int lane16 = lane & 15, quad = lane >> 4;
    int m0 = blockIdx.y * 128, n0 = blockIdx.x * 128;
    int wm = (wave >> 1) * 64, wn = (wave & 1) * 64;
    f32x4 acc[4][4] = {};

    for (int k0 = 0; k0 < K; k0 += 32) {
        __syncthreads();
        #pragma unroll
        for (int rep = 0; rep < 2; rep++) {
            int cc = tid + rep * 256;
            int row = cc >> 2, off = (cc & 3) * 8;
            *(bf16x8*)&sA[row * 40 + off] = *(const bf16x8*)&A[(size_t)(m0 + row) * K + k0 + off];
            *(bf16x8*)&sB[row * 40 + off] = *(const bf16x8*)&Bt[(size_t)(n0 + row) * K + k0 + off];
        }
        __syncthreads();
        bf16x8 af[4], bfr[4];
        #pragma unroll
        for (int t = 0; t < 4; t++) af[t]  = *(const bf16x8*)&sA[(wm + t * 16 + lane16) * 40 + quad * 8];
        #pragma unroll
        for (int t = 0; t < 4; t++) bfr[t] = *(const bf16x8*)&sB[(wn + t * 16 + lane16) * 40 + quad * 8];
        #pragma unroll
        for (int tm = 0; tm < 4; tm++)
            #pragma unroll
            for (int tn = 0; tn < 4; tn++)
                acc[tm][tn] = __builtin_amdgcn_mfma_f32_16x16x32_bf16(af[tm], bfr[tn], acc[tm][tn], 0, 0, 0);
    }

    float* Cf = (float*)Cout;
    u16* Ch = (u16*)Cout;
    #pragma unroll
    for (int tm = 0; tm < 4; tm++) {
        #pragma unroll
        for (int tn = 0; tn < 4; tn++) {
            int col = n0 + wn + tn * 16 + lane16;
            float bv_ = bias ? bias[col] : 0.f;
            #pragma unroll
            for (int r = 0; r < 4; r++) {
                int row = m0 + wm + tm * 16 + quad * 4 + r;
                float v = acc[tm][tn][r] + bv_;
                if (mode == GM_GELU_BF16) {
                    v = 0.5f * v * (1.f + erff(v * 0.70710678118654752f));
                    Ch[(size_t)row * N + col] = f2bf(v);
                } else if (mode == GM_BF16) {
                    Ch[(size_t)row * N + col] = f2bf(v);
                } else if (mode == GM_POSH) {
                    Ch[(((size_t)col >> 6) << 16) + ((size_t)row << 6) + (col & 63)] = f2bf(v);
                } else {
                    Cf[(size_t)row * N + col] = v;
                }
            }
        }
    }
}

// ---------------- V transpose: qkv[tok, 1536+h*64+d] -> Vt[(b,h), d, j] ----------------
__global__ __launch_bounds__(256) void k_vt(const u16* __restrict__ qkv, u16* __restrict__ Vt) {
    __shared__ u16 s[64][72];
    int z = blockIdx.y;  // b*12+h
    int j0 = blockIdx.x * 64;
    int b = z / NHn, h = z % NHn;
    int t = threadIdx.x;
    for (int e = t; e < 4096; e += 256) {
        int j = e >> 6, d = e & 63;
        s[j][d] = qkv[(size_t)(b * Sn + j0 + j) * 2304 + 1536 + h * 64 + d];
    }
    __syncthreads();
    for (int e = t; e < 4096; e += 256) {
        int d = e >> 6, jj = e & 63;
        Vt[((size_t)z * 64 + d) * Sn + j0 + jj] = s[jj][d];
    }
}

// ---------------- disentangled scores v2: LDS-staged windows + diagonal scatter ----------------
// posk/posq repacked per-head contiguous: [12][1024][64] bf16.
__global__ __launch_bounds__(256) void k_scores(const u16* __restrict__ qkv, const u16* __restrict__ poskR,
                                                const u16* __restrict__ posqR, u16* __restrict__ scores) {
    // LDS layout (u16 units): sQ[64*72], sK[64*72], sPK[128*72], sPQ[128*72]  = 55296 B
    __shared__ __align__(16) u16 smem[64 * 72 * 2 + 128 * 72 * 2];
    u16* sQ  = smem;
    u16* sK  = smem + 64 * 72;
    u16* sPK = smem + 64 * 72 * 2;
    u16* sPQ = smem + 64 * 72 * 2 + 128 * 72;
    float* s_acc = (float*)sPK;  // 64*65*4 = 16640 B, aliased over sPK after MFMA phase

    int z = blockIdx.z;
    int b = z / NHn, h = z % NHn;
    int i0 = blockIdx.y * 64, j0 = blockIdx.x * 64;
    int t = threadIdx.x, wave = t >> 6, lane = t & 63;
    int lane16 = lane & 15, quad = lane >> 4;

    for (int e = t; e < 512; e += 256) {
        int r = e >> 3, c = (e & 7) * 8;
        *(bf16x8*)&sQ[r * 72 + c] = *(const bf16x8*)&qkv[(size_t)(b * Sn + i0 + r) * 2304 + 0   + h * 64 + c];
        *(bf16x8*)&sK[r * 72 + c] = *(const bf16x8*)&qkv[(size_t)(b * Sn + j0 + r) * 2304 + 768 + h * 64 + c];
    }
    int r0pk = i0 - j0 + 449;  // window base into per-head pos rows (min 1, max 897)
    int r0pq = j0 - i0 + 449;
    const u16* pk = poskR + (size_t)h * 65536;
    const u16* pq = posqR + (size_t)h * 65536;
    for (int e = t; e < 1024; e += 256) {
        int r = e >> 3, c = (e & 7) * 8;
        *(bf16x8*)&sPK[r * 72 + c] = *(const bf16x8*)&pk[(size_t)min(r0pk + r, 1023) * 64 + c];
        *(bf16x8*)&sPQ[r * 72 + c] = *(const bf16x8*)&pq[(size_t)min(r0pq + r, 1023) * 64 + c];
    }
    __syncthreads();

    // A fragments (reused across all tiles)
    bf16x8 aq[2], ak[2];
    aq[0] = *(const bf16x8*)&sQ[(wave * 16 + lane16) * 72 + quad * 8];
    aq[1] = *(const bf16x8*)&sQ[(wave * 16 + lane16) * 72 + 32 + quad * 8];
    ak[0] = *(const bf16x8*)&sK[(wave * 16 + lane16) * 72 + quad * 8];
    ak[1] = *(const bf16x8*)&sK[(wave * 16 + lane16) * 72 + 32 + quad * 8];

    f32x4 a1[8], a2[8], cc[4];
    #pragma unroll
    for (int tr = 0; tr < 8; tr++) {
        f32x4 x = {}, y = {};
        #pragma unroll
        for (int kk = 0; kk < 2; kk++) {
            bf16x8 bpk = *(const bf16x8*)&sPK[(tr * 16 + lane16) * 72 + kk * 32 + quad * 8];
            bf16x8 bpq = *(const bf16x8*)&sPQ[(tr * 16 + lane16) * 72 + kk * 32 + quad * 8];
            x = __builtin_amdgcn_mfma_f32_16x16x32_bf16(aq[kk], bpk, x, 0, 0, 0);
            y = __builtin_amdgcn_mfma_f32_16x16x32_bf16(ak[kk], bpq, y, 0, 0, 0);
        }
        a1[tr] = x; a2[tr] = y;
    }
    #pragma unroll
    for (int tn = 0; tn < 4; tn++) {
        f32x4 x = {};
        #pragma unroll
        for (int kk = 0; kk < 2; kk++) {
            bf16x8 bk = *(const bf16x8*)&sK[(tn * 16 + lane16) * 72 + kk * 32 + quad * 8];
            x = __builtin_amdgcn_mfma_f32_16x16x32_bf16(aq[kk], bk, x, 0, 0, 0);
        }
        cc[tn] = x;
    }
    __syncthreads();  // all LDS reads done; sPK region becomes s_acc

    // scatter c2p: element (iL, t) -> scores(iL, jL= iL-t+63). Each wave owns its iL rows.
    #pragma unroll
    for (int tr = 0; tr < 8; tr++) {
        int tt = tr * 16 + lane16;
        #pragma unroll
        for (int r = 0; r < 4; r++) {
            int iL = wave * 16 + quad * 4 + r;
            int jL = iL - tt + 63;
            if (jL >= 0 && jL < 64) s_acc[iL * 65 + jL] = a1[tr][r];
        }
    }
    __syncthreads();
    // scatter p2c: element (jL, t) -> scores(iL= jL-t+63, jL), accumulate
    #pragma unroll
    for (int tr = 0; tr < 8; tr++) {
        int tt = tr * 16 + lane16;
        #pragma unroll
        for (int r = 0; r < 4; r++) {
            int jL = wave * 16 + quad * 4 + r;
            int iL = jL - tt + 63;
            if (iL >= 0 && iL < 64) s_acc[iL * 65 + jL] += a2[tr][r];
        }
    }
    __syncthreads();

    const float scale = 0.07216878364870323f;  // 1/sqrt(3*64)
    #pragma unroll
    for (int tn = 0; tn < 4; tn++) {
        #pragma unroll
        for (int r = 0; r < 4; r++) {
            int row = wave * 16 + quad * 4 + r;
            int col = tn * 16 + lane16;
            float v = cc[tn][r] + s_acc[row * 65 + col];
            scores[((size_t)z * Sn + i0 + row) * Sn + j0 + col] = f2bf(v * scale);
        }
    }
}

// ---------------- softmax (in-place, row = (b*12+h)*512 + i) ----------------
__global__ __launch_bounds__(256) void k_softmax(u16* __restrict__ scores, const float* __restrict__ mask) {
    int wave = threadIdx.x >> 6, lane = threadIdx.x & 63;
    long row = (long)blockIdx.x * 4 + wave;
    int b = (int)(row / (NHn * Sn));
    u16* p = scores + (size_t)row * Sn + lane * 8;
    const float* mrow = mask + (size_t)b * Sn + lane * 8;
    bf16x8 v = *(const bf16x8*)p;
    float s[8];
    #pragma unroll
    for (int j = 0; j < 8; j++) {
        float x = bf2f((u16)v[j]);
        s[j] = (mrow[j] > 0.f) ? x : -1e9f;
    }
    float mx = s[0];
    #pragma unroll
    for (int j = 1; j < 8; j++) mx = fmaxf(mx, s[j]);
    for (int off = 32; off; off >>= 1) mx = fmaxf(mx, __shfl_xor(mx, off));
    float sum = 0.f;
    #pragma unroll
    for (int j = 0; j < 8; j++) { s[j] = expf(s[j] - mx); sum += s[j]; }
    for (int off = 32; off; off >>= 1) sum += __shfl_xor(sum, off);
    float inv = 1.f / sum;
    bf16x8 o;
    #pragma unroll
    for (int j = 0; j < 8; j++) o[j] = (short)f2bf(s[j] * inv);
    *(bf16x8*)p = o;
}

// ---------------- attn @ V -> ctx bf16 [tok, h*64+d] ----------------
__global__ __launch_bounds__(256) void k_av(const u16* __restrict__ attn, const u16* __restrict__ Vt,
                                            u16* __restrict__ ctx) {
    __shared__ __align__(16) u16 sP[64 * 72];
    __shared__ __align__(16) u16 sV[64 * 72];
    int z = blockIdx.y;
    int b = z / NHn, h = z % NHn;
    int i0 = blockIdx.x * 64;
    int t = threadIdx.x, wave = t >> 6, lane = t & 63;
    int lane16 = lane & 15, quad = lane >> 4;
    f32x4 acc[4] = {};
    for (int j0 = 0; j0 < Sn; j0 += 64) {
        __syncthreads();
        for (int e = t; e < 512; e += 256) {
            int r = e >> 3, c = (e & 7) * 8;
            *(bf16x8*)&sP[r * 72 + c] = *(const bf16x8*)&attn[((size_t)z * Sn + i0 + r) * Sn + j0 + c];
            *(bf16x8*)&sV[r * 72 + c] = *(const bf16x8*)&Vt[((size_t)z * 64 + r) * Sn + j0 + c];
        }
        __syncthreads();
        #pragma unroll
        for (int kk = 0; kk < 2; kk++) {
            bf16x8 a = *(const bf16x8*)&sP[(wave * 16 + lane16) * 72 + kk * 32 + quad * 8];
            #pragma unroll
            for (int tn = 0; tn < 4; tn++) {
                bf16x8 bv = *(const bf16x8*)&sV[(tn * 16 + lane16) * 72 + kk * 32 + quad * 8];
                acc[tn] = __builtin_amdgcn_mfma_f32_16x16x32_bf16(a, bv, acc[tn], 0, 0, 0);
            }
        }
    }
    #pragma unroll
    for (int tn = 0; tn < 4; tn++)
        #pragma unroll
        for (int r = 0; r < 4; r++) {
            int row = i0 + wave * 16 + quad * 4 + r;  // i
            int col = tn * 16 + lane16;               // d
            ctx[(size_t)(b * Sn + row) * Hn + h * 64 + col] = f2bf(acc[tn][r]);
        }
}

// ---------------- residual + layernorm (optionally also bf16 copy) ----------------
__global__ __launch_bounds__(256) void k_ln(const float* __restrict__ x1, const float* __restrict__ x2,
                                            const float* __restrict__ g, const float* __restrict__ bb,
                                            float* __restrict__ outf, u16* __restrict__ outh) {
    int row = blockIdx.x, t = threadIdx.x;
    const float* p1 = x1 + (size_t)row * Hn;
    const float* p2 = x2 + (size_t)row * Hn;
    float x[3], s1 = 0.f, s2 = 0.f;
    #pragma unroll
    for (int i = 0; i < 3; i++) {
        int c = t + i * 256;
        float v = p1[c] + p2[c];
        x[i] = v; s1 += v; s2 += v * v;
    }
    for (int off = 32; off; off >>= 1) { s1 += __shfl_xor(s1, off); s2 += __shfl_xor(s2, off); }
    __shared__ float a1[4], a2[4];
    if ((t & 63) == 0) { a1[t >> 6] = s1; a2[t >> 6] = s2; }
    __syncthreads();
    s1 = a1[0] + a1[1] + a1[2] + a1[3];
    s2 = a2[0] + a2[1] + a2[2] + a2[3];
    float mu = s1 * (1.f / 768.f);
    float var = s2 * (1.f / 768.f) - mu * mu;
    float rs = rsqrtf(var + 1e-7f);
    #pragma unroll
    for (int i = 0; i < 3; i++) {
        int c = t + i * 256;
        float y = (x[i] - mu) * rs * g[c] + bb[c];
        outf[(size_t)row * Hn + c] = y;
        if (outh) outh[(size_t)row * Hn + c] = f2bf(y);
    }
}

extern "C" void kernel_launch(void* const* d_in, const int* in_sizes, int n_in,
                              void* d_out, int out_size, void* d_ws, size_t ws_size,
                              hipStream_t stream) {
    const float* hs   = (const float*)d_in[0];
    const float* mask = (const float*)d_in[1];
    const float* pos  = (const float*)d_in[2];
    const float* Wq = (const float*)d_in[3],  *bq = (const float*)d_in[4];
    const float* Wk = (const float*)d_in[5],  *bk = (const float*)d_in[6];
    const float* Wv = (const float*)d_in[7],  *bv = (const float*)d_in[8];
    const float* Wpk = (const float*)d_in[9], *Wpq = (const float*)d_in[10];
    const float* Wo = (const float*)d_in[11], *bo = (const float*)d_in[12];
    const float* g1 = (const float*)d_in[13], *b1ln = (const float*)d_in[14];
    const float* W1 = (const float*)d_in[15], *b1f = (const float*)d_in[16];
    const float* W2 = (const float*)d_in[17], *b2f = (const float*)d_in[18];
    const float* g2 = (const float*)d_in[19], *b2ln = (const float*)d_in[20];
    float* out = (float*)d_out;

    char* w = (char*)d_ws;
    u16*  X16    = (u16*)w;                 w += 12582912;   // [8192,768] bf16
    u16*  pos16  = (u16*)w;                 w += 1572864;    // [1024,768] bf16
    u16*  WqkvT  = (u16*)w;                 w += 3538944;    // [2304,768] bf16
    float* bqkv  = (float*)w;               w += 9216;       // [2304]
    u16*  WoT    = (u16*)w;                 w += 1179648;    // [768,768]
    u16*  W1T    = (u16*)w;                 w += 4718592;    // [3072,768]
    u16*  W2T    = (u16*)w;                 w += 4718592;    // [768,3072]
    u16*  WpkT   = (u16*)w;                 w += 1179648;
    u16*  WpqT   = (u16*)w;                 w += 1179648;
    u16*  posk   = (u16*)w;                 w += 1572864;    // [12][1024][64] bf16 per-head
    u16*  posq   = (u16*)w;                 w += 1572864;
    u16*  qkv    = (u16*)w;                 w += 37748736;   // [8192,2304] bf16
    u16*  Vt     = (u16*)w;                 w += 12582912;   // [192,64,512] bf16
    u16*  scores = (u16*)w;                 w += 100663296;  // [192,512,512] bf16
    float* attnout = (float*)w;             w += 25165824;   // [8192,768] f32
    // aliases (lifetime-disjoint)
    u16*  ctx  = qkv;                         // written by AV after q,k,v dead
    float* h1f = (float*)scores;              // after attn consumed
    u16*  ffn1 = (u16*)((char*)scores + 25165824);
    u16*  h1h  = X16;                         // X16 dead after qkv GEMM
    float* ffn2 = attnout;                    // attnout dead after LN1

    // prep: converts + weight transposes
    k_cvt<<<3072, 256, 0, stream>>>(hs, X16, TOK * Hn);
    k_cvt<<<384, 256, 0, stream>>>(pos, pos16, 1024 * Hn);
    dim3 tb(32, 8);
    k_transpose<<<dim3(24, 24), tb, 0, stream>>>(Wq, WqkvT, 768, 768);
    k_transpose<<<dim3(24, 24), tb, 0, stream>>>(Wk, WqkvT + 589824, 768, 768);
    k_transpose<<<dim3(24, 24), tb, 0, stream>>>(Wv, WqkvT + 1179648, 768, 768);
    k_transpose<<<dim3(24, 24), tb, 0, stream>>>(Wo, WoT, 768, 768);
    k_transpose<<<dim3(96, 24), tb, 0, stream>>>(W1, W1T, 768, 3072);
    k_transpose<<<dim3(24, 96), tb, 0, stream>>>(W2, W2T, 3072, 768);
    k_transpose<<<dim3(24, 24), tb, 0, stream>>>(Wpk, WpkT, 768, 768);
    k_transpose<<<dim3(24, 24), tb, 0, stream>>>(Wpq, WpqT, 768, 768);
    k_pack_bias<<<9, 256, 0, stream>>>(bq, bk, bv, bqkv);

    // projections
    k_gemm<<<dim3(18, 64), 256, 0, stream>>>(X16, WqkvT, bqkv, qkv, TOK, 2304, 768, GM_BF16);
    k_gemm<<<dim3(6, 8), 256, 0, stream>>>(pos16, WpkT, nullptr, posk, 1024, 768, 768, GM_POSH);
    k_gemm<<<dim3(6, 8), 256, 0, stream>>>(pos16, WpqT, nullptr, posq, 1024, 768, 768, GM_POSH);

    // attention
    k_vt<<<dim3(8, 192), 256, 0, stream>>>(qkv, Vt);
    k_scores<<<dim3(8, 8, 192), 256, 0, stream>>>(qkv, posk, posq, scores);
    k_softmax<<<24576, 256, 0, stream>>>(scores, mask);
    k_av<<<dim3(8, 192), 256, 0, stream>>>(scores, Vt, ctx);
    k_gemm<<<dim3(6, 64), 256, 0, stream>>>(ctx, WoT, bo, attnout, TOK, 768, 768, GM_F32);
    k_ln<<<TOK, 256, 0, stream>>>(hs, attnout, g1, b1ln, h1f, h1h);

    // FFN
    k_gemm<<<dim3(24, 64), 256, 0, stream>>>(h1h, W1T, b1f, ffn1, TOK, 3072, 768, GM_GELU_BF16);
    k_gemm<<<dim3(6, 64), 256, 0, stream>>>(ffn1, W2T, b2f, ffn2, TOK, 768, 3072, GM_F32);
    k_ln<<<TOK, 256, 0, stream>>>(h1f, ffn2, g2, b2ln, out, nullptr);
}